// Round 4
// baseline (235.458 us; speedup 1.0000x reference)
//
#include <hip/hip_runtime.h>
#include <stdint.h>

// ReconstructionDecoder: out[b,n,t,f,:] = relu(LN(x[b,n]+t_emb[t]+f_emb[f]) @ W1 + b1) @ W2 + b2
// B=2 N=8 T=128 F=128 D=256 E=512.  Rows M = 262144.
//
// Round 4: raise arithmetic intensity (r3 was structure/latency-bound at MfmaUtil 22%).
//  - 512-thr blocks, 64 rows/wave (afrag[4][8]): each ds_read_b128 B-frag feeds 4 MFMAs.
//    launch_bounds(512,2) -> 1 block/CU, 256-VGPR budget, demand ~205 -> no spill.
//  - fragB file is now plain W1gT bf16 [e][k] (g*W1 transposed): the 16B granule
//    (8 consecutive k of one e) is contiguous, so global_load_lds gathers it per-lane;
//    prep becomes a coalesced LDS-staged transpose (r3 prep had fully-scattered reads).
//  - grid 512 = exactly 2 sequential blocks/CU; 16 chunks x 32 e-cols, 1 barrier/chunk.

#define D_ 256
#define E_ 512

typedef __attribute__((ext_vector_type(8))) short short8;
typedef __attribute__((ext_vector_type(4))) float f32x4;

typedef __attribute__((address_space(1))) void gvoid;
typedef __attribute__((address_space(3))) void lvoid;
#define GLOAD_LDS16(g, l) \
  __builtin_amdgcn_global_load_lds((gvoid*)(g), (lvoid*)(l), 16, 0, 0)

__device__ inline unsigned short f2bf(float f) {
  unsigned int u = __float_as_uint(f);
  u += 0x7fffu + ((u >> 16) & 1u);
  return (unsigned short)(u >> 16);
}

// prep: blocks 0..31  -> w1t[e][k] = bf16(ln_g[k]*W1[k][e])  (16 e-rows per block)
//       blocks 32..63 -> b1p[e] = b1[e] + sum_k ln_b[k]*W1[k][e] (16 e per block)
__global__ __launch_bounds__(256) void prep(const float* __restrict__ W1,
                                            const float* __restrict__ ln_g,
                                            const float* __restrict__ ln_b,
                                            const float* __restrict__ b1,
                                            unsigned short* __restrict__ w1t,
                                            float* __restrict__ b1p) {
  __shared__ float s[256 * 17];
  const int blk = blockIdx.x;
  const int tid = threadIdx.x;
  if (blk < 32) {
    const int e0 = blk * 16;
    // read coalesced: 16 consecutive e per 16 lanes
#pragma unroll
    for (int it = 0; it < 16; ++it) {
      int k = it * 16 + (tid >> 4);
      int ep = tid & 15;
      s[k * 17 + ep] = ln_g[k] * W1[k * E_ + e0 + ep];
    }
    __syncthreads();
    // write coalesced: 16B granules of 8 consecutive k within one e-row
#pragma unroll
    for (int it = 0; it < 2; ++it) {
      int g = it * 256 + tid;
      int ep = g >> 5;           // 0..15
      int k0 = (g & 31) * 8;     // 0..248
      union { unsigned short u[8]; float4 v; } pk;
#pragma unroll
      for (int j = 0; j < 8; ++j) pk.u[j] = f2bf(s[(k0 + j) * 17 + ep]);
      *reinterpret_cast<float4*>(w1t + (e0 + ep) * D_ + k0) = pk.v;
    }
  } else {
    int bb = blk - 32;         // 0..31, 16 e's per block
    int e = bb * 16 + (tid & 15);
    int kb = (tid >> 4) * 16;  // 16 threads per e, 16 k's per thread
    float p = 0.f;
    for (int i = 0; i < 16; ++i) p = fmaf(ln_b[kb + i], W1[(kb + i) * E_ + e], p);
    s[tid] = p;
    __syncthreads();
    if (tid < 16) {
      float ssum = b1[bb * 16 + tid];
      for (int g = 0; g < 16; ++g) ssum += s[g * 16 + tid];
      b1p[bb * 16 + tid] = ssum;
    }
  }
}

__global__ __launch_bounds__(512, 2) void decoder_main(
    const float* __restrict__ x, const float* __restrict__ t_emb,
    const float* __restrict__ f_emb, const unsigned short* __restrict__ w1t,
    const float* __restrict__ b1p, const float* __restrict__ W2,
    const float* __restrict__ b2, float* __restrict__ out) {
  __shared__ short8 s_frag[2][1024];  // 2 x 16KB ping-pong (one 32-e chunk each)
  __shared__ float s_xt[4 * D_];      // x[b,n,:]+t_emb[t0+tl,:], tl=0..3
  __shared__ float s_b1[E_];
  __shared__ float s_w2[2 * E_];
  __shared__ float s_out[1024];

  const int tid = threadIdx.x;   // 0..511
  const int wave = tid >> 6;     // 0..7
  const int lane = tid & 63;
  const int quad = (lane >> 4) & 3;
  const int n16 = lane & 15;
  const int bIdx = blockIdx.x;   // 512 blocks: bn(16) x t-quad(32)
  const int bn = bIdx >> 5;
  const int t0 = (bIdx & 31) * 4;
  const int k0 = wave * 32 + quad * 8;  // this lane's granule k-base (= ks*32+quad*8, ks=wave)

  // cooperative stage of per-block constants
  {
    int d = tid & 255, tl = tid >> 8;  // tl = 0,1 then +2
    float xv = x[bn * D_ + d];
    s_xt[tl * D_ + d] = xv + t_emb[(t0 + tl) * D_ + d];
    s_xt[(tl + 2) * D_ + d] = xv + t_emb[(t0 + tl + 2) * D_ + d];
  }
  s_b1[tid] = b1p[tid];
  s_w2[tid] = W2[tid];
  s_w2[tid + 512] = W2[tid + 512];
  __syncthreads();

  // async-stage chunk 0 (flies during the A-build); call i covers jl=i, ks=wave
#pragma unroll
  for (int i = 0; i < 2; ++i)
    GLOAD_LDS16(w1t + (i * 16 + n16) * D_ + k0, &s_frag[0][i * 512 + wave * 64]);

  // ---- build A fragments (LN-normalized h, bf16) for 4 row-groups of 16 ----
  short8 afrag[4][8];
#pragma unroll
  for (int g = 0; g < 4; ++g) {
    const int lr = wave * 64 + g * 16 + n16;  // local row 0..511
    const float4* fe = reinterpret_cast<const float4*>(f_emb + (lr & 127) * D_);
    const float4* xt4 = reinterpret_cast<const float4*>(s_xt + (lr >> 7) * D_);
    float sum = 0.f, sq = 0.f;
#pragma unroll
    for (int ks = 0; ks < 8; ++ks) {
      int i0 = ks * 8 + quad * 2;
      float4 a0 = xt4[i0], a1 = xt4[i0 + 1];
      float4 c0 = fe[i0], c1 = fe[i0 + 1];
      float h0 = a0.x + c0.x, h1 = a0.y + c0.y, h2 = a0.z + c0.z, h3 = a0.w + c0.w;
      float h4 = a1.x + c1.x, h5 = a1.y + c1.y, h6 = a1.z + c1.z, h7 = a1.w + c1.w;
      sum += (h0 + h1 + h2 + h3) + (h4 + h5 + h6 + h7);
      sq = fmaf(h0, h0, sq); sq = fmaf(h1, h1, sq);
      sq = fmaf(h2, h2, sq); sq = fmaf(h3, h3, sq);
      sq = fmaf(h4, h4, sq); sq = fmaf(h5, h5, sq);
      sq = fmaf(h6, h6, sq); sq = fmaf(h7, h7, sq);
    }
    // row's 256 elems live in lanes {l, l^16, l^32, l^48}
    sum += __shfl_xor(sum, 16); sum += __shfl_xor(sum, 32);
    sq  += __shfl_xor(sq, 16);  sq  += __shfl_xor(sq, 32);
    float mu = sum * (1.0f / 256.0f);
    float var = sq * (1.0f / 256.0f) - mu * mu;
    float rs = rsqrtf(var + 1e-5f);
    float cc = -mu * rs;
#pragma unroll
    for (int ks = 0; ks < 8; ++ks) {
      int i0 = ks * 8 + quad * 2;
      float4 a0 = xt4[i0], a1 = xt4[i0 + 1];
      float4 c0 = fe[i0], c1 = fe[i0 + 1];
      union { unsigned short u[8]; short8 v; } fr;
      fr.u[0] = f2bf(fmaf(a0.x + c0.x, rs, cc));
      fr.u[1] = f2bf(fmaf(a0.y + c0.y, rs, cc));
      fr.u[2] = f2bf(fmaf(a0.z + c0.z, rs, cc));
      fr.u[3] = f2bf(fmaf(a0.w + c0.w, rs, cc));
      fr.u[4] = f2bf(fmaf(a1.x + c1.x, rs, cc));
      fr.u[5] = f2bf(fmaf(a1.y + c1.y, rs, cc));
      fr.u[6] = f2bf(fmaf(a1.z + c1.z, rs, cc));
      fr.u[7] = f2bf(fmaf(a1.w + c1.w, rs, cc));
      afrag[g][ks] = fr.v;
    }
  }

  // ---- main loop: 16 chunks x (2 col-tiles x 8 K-steps x 4 row-groups) ----
  float oa[4][4][2] = {};
  for (int s = 0; s < 16; ++s) {
    __syncthreads();  // drains this wave's async loads; all waves' buf[s&1] visible
    if (s < 15) {
      const unsigned short* wch = w1t + (s + 1) * 32 * D_;
      short8* nb = s_frag[(s + 1) & 1];
#pragma unroll
      for (int i = 0; i < 2; ++i)
        GLOAD_LDS16(wch + (i * 16 + n16) * D_ + k0, &nb[i * 512 + wave * 64]);
    }
    const short8* bf8 = s_frag[s & 1];
#pragma unroll
    for (int jl = 0; jl < 2; ++jl) {
      f32x4 acc[4];
#pragma unroll
      for (int g = 0; g < 4; ++g) acc[g] = (f32x4){0.f, 0.f, 0.f, 0.f};
#pragma unroll
      for (int ks = 0; ks < 8; ++ks) {
        short8 bf = bf8[(jl * 8 + ks) * 64 + lane];
#pragma unroll
        for (int g = 0; g < 4; ++g)
          acc[g] = __builtin_amdgcn_mfma_f32_16x16x32_bf16(afrag[g][ks], bf, acc[g], 0, 0, 0);
      }
      int e = s * 32 + jl * 16 + n16;
      float bias = s_b1[e];
      float w0 = s_w2[2 * e], w1v = s_w2[2 * e + 1];
#pragma unroll
      for (int g = 0; g < 4; ++g)
#pragma unroll
        for (int r = 0; r < 4; ++r) {
          float y = fmaxf(acc[g][r] + bias, 0.f);
          oa[g][r][0] += y * w0;
          oa[g][r][1] += y * w1v;
        }
    }
  }

  // ---- reduce over the 16 column-lanes, stage, coalesced store ----
#pragma unroll
  for (int g = 0; g < 4; ++g)
#pragma unroll
    for (int r = 0; r < 4; ++r)
#pragma unroll
      for (int o = 0; o < 2; ++o) {
        float v = oa[g][r][o];
        v += __shfl_xor(v, 1);
        v += __shfl_xor(v, 2);
        v += __shfl_xor(v, 4);
        v += __shfl_xor(v, 8);
        oa[g][r][o] = v;
      }
  if (n16 == 0) {
#pragma unroll
    for (int g = 0; g < 4; ++g)
#pragma unroll
      for (int r = 0; r < 4; ++r) {
        int lrow = wave * 64 + g * 16 + quad * 4 + r;  // local row
        s_out[lrow * 2 + 0] = oa[g][r][0];
        s_out[lrow * 2 + 1] = oa[g][r][1];
      }
  }
  __syncthreads();
  out[bIdx * 1024 + tid] = s_out[tid] + b2[tid & 1];
  out[bIdx * 1024 + 512 + tid] = s_out[512 + tid] + b2[tid & 1];
}

extern "C" void kernel_launch(void* const* d_in, const int* in_sizes, int n_in,
                              void* d_out, int out_size, void* d_ws, size_t ws_size,
                              hipStream_t stream) {
  const float* x = (const float*)d_in[0];
  const float* t_emb = (const float*)d_in[1];
  const float* f_emb = (const float*)d_in[2];
  const float* ln_g = (const float*)d_in[3];
  const float* ln_b = (const float*)d_in[4];
  const float* W1 = (const float*)d_in[5];
  const float* b1 = (const float*)d_in[6];
  const float* W2 = (const float*)d_in[7];
  const float* b2 = (const float*)d_in[8];

  unsigned short* w1t = (unsigned short*)d_ws;      // 512x256 bf16 = 256KB
  float* b1p = (float*)((char*)d_ws + 131072 * 2);  // 2KB

  prep<<<64, 256, 0, stream>>>(W1, ln_g, ln_b, b1, w1t, b1p);
  decoder_main<<<512, 512, 0, stream>>>(x, t_emb, f_emb, w1t, b1p, W2, b2,
                                        (float*)d_out);
}